// Round 12
// baseline (136.946 us; speedup 1.0000x reference)
//
#include <hip/hip_runtime.h>
#include <hip/hip_bf16.h>
#include <math.h>

#define B_N 8192
#define D_K 256
#define TILE 128
#define NT 1024
#define NBLK 64             // B_N / TILE
#define NPAIR 2080          // NBLK*(NBLK+1)/2 upper-triangular tile pairs
#define NCLS 100
#define KEXP 28.8539008177792681f   // 20*log2(e): e^(sim-20) = 2^((dot-1)*KEXP)

typedef __attribute__((ext_vector_type(8))) short short8;
typedef __attribute__((ext_vector_type(16))) float f32x16;

__device__ __forceinline__ unsigned short f2bf(float x) {
    unsigned int u = __float_as_uint(x);
    unsigned int r = (u + 0x7FFFu + ((u >> 16) & 1u)) >> 16;
    return (unsigned short)r;
}

// async global->LDS, 16B per lane: dest = (wave-uniform) lds base + lane*16
__device__ __forceinline__ void gload_lds16(const short* g, short* l) {
    __builtin_amdgcn_global_load_lds(
        (const __attribute__((address_space(1))) void*)g,
        (__attribute__((address_space(3))) void*)l, 16, 0, 0);
}

// sum over each aligned 16-lane group on the VALU pipe (DPP). Verified r9/r10 (absmax 0).
__device__ __forceinline__ float row_sum16(float v) {
    v += __int_as_float(__builtin_amdgcn_update_dpp(0, __float_as_int(v), 0xB1, 0xF, 0xF, true));
    v += __int_as_float(__builtin_amdgcn_update_dpp(0, __float_as_int(v), 0x4E, 0xF, 0xF, true));
    v += __int_as_float(__builtin_amdgcn_update_dpp(0, __float_as_int(v), 0x141, 0xF, 0xF, true));
    v += __int_as_float(__builtin_amdgcn_update_dpp(0, __float_as_int(v), 0x140, 0xF, 0xF, true));
    return v;
}

// -------- Kernel 1: normalize rows -> bf16; block 0 also: label hist + zero accums --------
__global__ void prep_kernel(const float* __restrict__ feat, unsigned short* __restrict__ fnorm,
                            const int* __restrict__ labels, int* __restrict__ cnt,
                            float* __restrict__ gscal, double* __restrict__ accum,
                            unsigned int* __restrict__ done) {
    if (blockIdx.x == 0) {
        __shared__ int h[NCLS];
        int t = threadIdx.x;
        if (t < NCLS) h[t] = 0;
        if (t == 0) {
            gscal[0] = 0.f; gscal[1] = 0.f;
            accum[0] = 0.0; accum[1] = 0.0; accum[2] = 0.0;
            *done = 0u;
        }
        __syncthreads();
        for (int r = t; r < B_N; r += 256) atomicAdd(&h[labels[r]], 1);
        __syncthreads();
        if (t < NCLS) cnt[t] = h[t];
    }
    int wave = threadIdx.x >> 6, lane = threadIdx.x & 63;
    int row = blockIdx.x * 4 + wave;
    float4 v = *(const float4*)(feat + (size_t)row * D_K + lane * 4);
    float ss = v.x * v.x + v.y * v.y + v.z * v.z + v.w * v.w;
    #pragma unroll
    for (int off = 1; off < 64; off <<= 1) ss += __shfl_xor(ss, off);
    float inv = 1.0f / fmaxf(sqrtf(ss), 1e-12f);
    ushort4 o;
    o.x = f2bf(v.x * inv); o.y = f2bf(v.y * inv);
    o.z = f2bf(v.z * inv); o.w = f2bf(v.w * inv);
    *(ushort4*)(fnorm + (size_t)row * D_K + lane * 4) = o;
}

// -------- Kernel 2: upper-triangular sim tiles; 16 waves x 32x32 (mfma 32x32x16) --------
// acc = 16 regs/lane -> total ~56 regs -> 8 waves/SIMD (2 blocks/CU, 32 waves/CU).
// Staging LDS[r][c] = global chunk (c ^ (r&7)); frag read chunk = want ^ (row&7).
__global__ __launch_bounds__(NT, 8) void main_kernel(
        const unsigned short* __restrict__ fnorm, const int* __restrict__ labels,
        float2* __restrict__ G, float* __restrict__ gscal) {
    int bid = blockIdx.x;
    int b = (int)((sqrtf(8.0f * bid + 1.0f) - 1.0f) * 0.5f);
    while ((b + 1) * (b + 2) / 2 <= bid) ++b;
    while (b * (b + 1) / 2 > bid) --b;
    int a = bid - b * (b + 1) / 2;
    const int row0 = a * TILE, col0 = b * TILE;
    const bool diag = (a == b);

    __shared__ short As[TILE * 64];    // 16 KB; reused as Rbuf float2[4][128]
    __shared__ short Bs[TILE * 64];    // 16 KB; reused as Cbuf float2[4][128]
    __shared__ int Ls[2 * TILE];
    __shared__ int ghs[16];
    __shared__ float gps[16];

    const int tid = threadIdx.x;
    const int lane = tid & 63, wave = tid >> 6;
    const int wm = wave >> 2, wn = wave & 3;    // 4x4 waves; each 32x32
    const int l31 = lane & 31, lhf = lane >> 5;
    const short* fn = (const short*)fnorm;

    // staging coords: 1024 threads cover 128 rows x 8 chunks of 16B
    const int rs = tid >> 3, cs = (tid & 7) ^ (rs & 7);
    const int ub = (tid & ~63) * 8;            // wave-uniform LDS short offset

    if (tid < 128) Ls[tid] = labels[row0 + tid];
    else if (tid < 256) Ls[tid] = labels[col0 + tid - 128];
    if (lane == 0) ghs[wave] = 0;

    f32x16 acc;
    #pragma unroll
    for (int i = 0; i < 16; i++) acc[i] = 0.f;

    for (int kc = 0; kc < 4; ++kc) {
        gload_lds16(fn + (size_t)(row0 + rs) * D_K + kc * 64 + cs * 8, &As[ub]);
        if (!diag)
            gload_lds16(fn + (size_t)(col0 + rs) * D_K + kc * 64 + cs * 8, &Bs[ub]);
        __syncthreads();
        const short* Bsrc = diag ? As : Bs;
        const int arow = wm * 32 + l31, brow = wn * 32 + l31;
        #pragma unroll
        for (int kch = 0; kch < 4; ++kch) {     // 4 x K=16 per 64-K stage
            int cha = (kch * 2 + lhf) ^ (l31 & 7);
            short8 af = *(const short8*)&As[arow * 64 + cha * 8];
            short8 bf = *(const short8*)&Bsrc[brow * 64 + cha * 8];
            acc = __builtin_amdgcn_mfma_f32_32x32x16_bf16(af, bf, acc, 0, 0, 0);
        }
        __syncthreads();
    }

    // ---- Epilogue. 32x32 C/D layout: col = lane&31, row = (reg&3)+8*(reg>>2)+4*(lane>>5) ----
    float2* Rbuf = (float2*)As;   // [wn 0..3][128]
    float2* Cbuf = (float2*)Bs;   // [wm 0..3][128]

    const int colg = col0 + wn * 32 + l31;     // reg-invariant for this lane
    const int lc = Ls[128 + wn * 32 + l31];

    float cD = 0.f, gp = 0.f;
    unsigned int hmask = 0;                    // bit reg = high

    #pragma unroll
    for (int reg = 0; reg < 16; reg++) {
        int rloc = wm * 32 + (reg & 3) + 8 * (reg >> 2) + 4 * lhf;
        int rowg = row0 + rloc;
        int lr = Ls[rloc];
        float dot = acc[reg];
        float e = __builtin_exp2f((dot - 1.0f) * KEXP);   // e^(sim-20), sim<=20
        bool ns = (rowg != colg);
        float ev = ns ? e : 0.f;
        cD += ev;
        bool ps = ns && (lr == lc);
        gp += ps ? dot : 0.f;
        bool hi = ps && (dot > 0.7f);
        hmask |= hi ? (1u << reg) : 0u;
        // row sum across the 32 lanes sharing this row (same half)
        float d = row_sum16(ev);
        d += __shfl_xor(d, 16);
        if (l31 == 0) Rbuf[wn * 128 + rloc] = {d, 0.f};
    }

    if (!diag) {
        cD += __shfl_xor(cD, 32);              // combine halves -> full 32-row column sum
        if (lhf == 0) Cbuf[wm * 128 + wn * 32 + l31] = {cD, 0.f};
    }

    // gp wave reduction
    gp = row_sum16(gp);
    gp += __shfl_xor(gp, 16);
    gp += __shfl_xor(gp, 32);
    if (lane == 0) gps[wave] = gp;

    // ---- Rare path: any high-similarity positive in this wave ----
    if (__any(hmask != 0)) {
        float cR = 0.f;
        #pragma unroll
        for (int reg = 0; reg < 16; reg++) {
            int rloc = wm * 32 + (reg & 3) + 8 * (reg >> 2) + 4 * lhf;
            float rx = 0.f;
            if (hmask & (1u << reg)) {
                rx = __builtin_exp2f((acc[reg] - 1.0f) * KEXP);
                cR += rx;
            }
            rx = row_sum16(rx);
            rx += __shfl_xor(rx, 16);
            if (l31 == 0) Rbuf[wn * 128 + rloc].y = rx;
        }
        if (!diag) {
            cR += __shfl_xor(cR, 32);
            if (lhf == 0) Cbuf[wm * 128 + wn * 32 + l31].y = cR;
        }
        int nhi = __popc(hmask);
        #pragma unroll
        for (int off = 1; off < 64; off <<= 1) nhi += __shfl_xor(nhi, off);
        if (lane == 0) ghs[wave] = nhi;
    }
    __syncthreads();

    if (tid < 128) {
        int r = tid;
        float2 a0 = Rbuf[r], a1 = Rbuf[128 + r], a2 = Rbuf[256 + r], a3 = Rbuf[384 + r];
        G[(size_t)b * B_N + row0 + r] = {a0.x + a1.x + a2.x + a3.x, a0.y + a1.y + a2.y + a3.y};
    } else if (tid < 256 && !diag) {
        int c = tid - 128;
        float2 a0 = Cbuf[c], a1 = Cbuf[128 + c], a2 = Cbuf[256 + c], a3 = Cbuf[384 + c];
        G[(size_t)a * B_N + col0 + c] = {a0.x + a1.x + a2.x + a3.x, a0.y + a1.y + a2.y + a3.y};
    }
    if (tid == 0) {
        float w = diag ? 1.0f : 2.0f;   // off-diag tile stands for (i,j) and (j,i)
        float gpt = 0.f;
        int tot = 0;
        #pragma unroll
        for (int i = 0; i < 16; i++) { gpt += gps[i]; tot += ghs[i]; }
        atomicAdd(&gscal[0], w * gpt);
        if (tot > 0) atomicAdd(&gscal[1], w * (float)tot);
    }
}

// -------- Kernel 3: per-row reduction over 64 slots + last-block final assembly --------
__global__ void finalize_kernel(const float2* __restrict__ G, const int* __restrict__ labels,
                                const int* __restrict__ cnt, const float* __restrict__ gscal,
                                double* __restrict__ accum, unsigned int* __restrict__ done,
                                float* __restrict__ out) {
    int lane = threadIdx.x & 63, q = threadIdx.x >> 6;   // q = slot quarter
    int r = blockIdx.x * 64 + lane;
    float d = 0.f, rx = 0.f;
    #pragma unroll
    for (int s = 0; s < 16; ++s) {
        float2 g = G[(size_t)(q * 16 + s) * B_N + r];
        d += g.x; rx += g.y;
    }
    __shared__ float2 sh[4][64];
    sh[q][lane] = {d, rx};
    __syncthreads();
    if (threadIdx.x < 64) {
        int rr = blockIdx.x * 64 + threadIdx.x;
        float2 t0 = sh[0][threadIdx.x], t1 = sh[1][threadIdx.x];
        float2 t2 = sh[2][threadIdx.x], t3 = sh[3][threadIdx.x];
        float dd = t0.x + t1.x + t2.x + t3.x;
        float rr2 = t0.y + t1.y + t2.y + t3.y;
        float np = (float)(cnt[labels[rr]] - 1);
        float ld = logf(dd + 1e-12f) + 20.0f;             // log_denom (shift 20)
        double s1 = (double)np * (double)ld;
        double s2 = (double)np;
        double s3 = (rr2 > 0.f) ? (double)logf(rr2 + 1.0f) : 0.0;  // baseline=0: sim_max=20
        #pragma unroll
        for (int off = 1; off < 64; off <<= 1) {
            s1 += __shfl_xor(s1, off);
            s2 += __shfl_xor(s2, off);
            s3 += __shfl_xor(s3, off);
        }
        if (threadIdx.x == 0) {
            atomicAdd(&accum[0], s1);
            atomicAdd(&accum[1], s2);
            atomicAdd(&accum[2], s3);
            __threadfence();
            unsigned int tk = atomicAdd(done, 1u);
            if (tk == gridDim.x - 1) {           // last block assembles the scalar
                double a1 = atomicAdd(&accum[0], 0.0);
                double a2 = atomicAdd(&accum[1], 0.0);
                double a3 = atomicAdd(&accum[2], 0.0);
                double gp = (double)gscal[0];    // sum over ordered pos pairs of dot
                double gh = (double)gscal[1];    // count of high ordered pairs
                double scl = (a2 > 0.0) ? (a1 - 20.0 * gp) / fmax(a2, 1.0) : 0.0;
                double rel = (gh > 0.0) ? a3 / fmax(gh, 1.0) : 0.0;
                double tot = scl + rel;          // BETA = 1.0
                tot = fmin(fmax(tot, 0.0), 10.0);
                out[0] = (float)tot;
            }
        }
    }
}

extern "C" void kernel_launch(void* const* d_in, const int* in_sizes, int n_in,
                              void* d_out, int out_size, void* d_ws, size_t ws_size,
                              hipStream_t stream) {
    const float* feat = (const float*)d_in[0];
    const int* labels = (const int*)d_in[1];
    float* out = (float*)d_out;
    char* ws = (char*)d_ws;

    unsigned short* fnorm = (unsigned short*)(ws);                          // 4 MB
    float2* G          = (float2*)(ws + (size_t)4 * 1024 * 1024);           // 4 MB: [64][8192]
    int*    cnt        = (int*)(ws + (size_t)8 * 1024 * 1024);              // 400 B
    float*  gscal      = (float*)(ws + (size_t)8 * 1024 * 1024 + 1024);     // 8 B
    double* accum      = (double*)(ws + (size_t)8 * 1024 * 1024 + 2048);    // 24 B
    unsigned int* done = (unsigned int*)(ws + (size_t)8 * 1024 * 1024 + 3072); // 4 B

    prep_kernel<<<B_N / 4, 256, 0, stream>>>(feat, fnorm, labels, cnt, gscal, accum, done);
    main_kernel<<<NPAIR, NT, 0, stream>>>(fnorm, labels, G, gscal);
    finalize_kernel<<<B_N / 64, 256, 0, stream>>>(G, labels, cnt, gscal, accum, done, out);
    (void)in_sizes; (void)n_in; (void)out_size; (void)ws_size;
}